// Round 10
// baseline (2500.331 us; speedup 1.0000x reference)
//
#include <hip/hip_runtime.h>
#include <hip/hip_bf16.h>
#include <math.h>

// Model dims
#define Bq   16
#define Tq   128
#define Hq   512
#define Dq   256
#define G4H  2048            // 4*H
#define MR   2048            // B*T rows
#define VO   32001           // VOUT+1
#define NPAD 32128           // VO padded to multiple of 128
#define BH   (Bq * Hq)       // 8192
#define SENTW 0x7FC0u        // bf16 NaN sentinel (h is bounded, never NaN)
#define SENT64 0x7FC07FC07FC07FC0ull
#define NANW 0x7FC00000u     // f32 NaN sentinel for finals
#define SPINCAP (1 << 20)    // bounded spins: wrong-answer-not-hang on bug

typedef unsigned int u32;
typedef unsigned long long u64;
typedef __attribute__((ext_vector_type(4))) float f32x4;
typedef __attribute__((ext_vector_type(8))) short bfrag;   // 8 x bf16 (4 VGPRs)
typedef __attribute__((ext_vector_type(4))) float facc;    // mfma accumulator

__device__ __forceinline__ float bf2f(short s) {
  union { unsigned u; float f; } v; v.u = ((unsigned)(unsigned short)s) << 16; return v.f;
}
__device__ __forceinline__ short f2bf(float f) {
  union { float f; unsigned u; } v; v.f = f;
  unsigned r = (v.u + 0x7fffu + ((v.u >> 16) & 1u)) >> 16;
  return (short)r;
}
__device__ __forceinline__ float asf(u32 u) {
  union { u32 u; float f; } v; v.u = u; return v.f;
}
__device__ __forceinline__ u32 fbits(float f) {
  union { float f; u32 u; } v; v.f = f; return v.u;
}
__device__ __forceinline__ float sigm(float x) { return 1.0f / (1.0f + expf(-x)); }

__device__ __forceinline__ void ic_store64(u64* p, u64 v) {
  __hip_atomic_store(p, v, __ATOMIC_RELAXED, __HIP_MEMORY_SCOPE_AGENT);
}
__device__ __forceinline__ u64 ic_load64(const u64* p) {
  return __hip_atomic_load(p, __ATOMIC_RELAXED, __HIP_MEMORY_SCOPE_AGENT);
}
__device__ __forceinline__ void ic_store32(u32* p, u32 v) {
  __hip_atomic_store(p, v, __ATOMIC_RELAXED, __HIP_MEMORY_SCOPE_AGENT);
}
__device__ __forceinline__ u32 ic_load32(const u32* p) {
  return __hip_atomic_load(p, __ATOMIC_RELAXED, __HIP_MEMORY_SCOPE_AGENT);
}

// ---- XOR-swizzled LDS addressing for a [16][520]-short plane (row stride 1040B)
__device__ __forceinline__ void* swz(void* plane, int row, int byteoff) {
  return (void*)((char*)plane + row * 1040 + (byteoff ^ ((row & 7) << 4)));
}

// ---- stage helpers (plane = 16 rows x 256 u32)
__device__ __forceinline__ void stage_h(void* p0, void* p1, const u64 v[8]) {
  #pragma unroll
  for (int it = 0; it < 8; ++it) {
    int i = it * 512 + threadIdx.x;
    int b = i >> 8, bo = (i & 255) * 4;
    *(u32*)swz(p0, b, bo) = (u32)v[it];
    *(u32*)swz(p1, b, bo) = (u32)(v[it] >> 32);
  }
}
__device__ __forceinline__ void stage_x(void* p0, const u32 w[8]) {
  #pragma unroll
  for (int it = 0; it < 8; ++it) {
    int i = it * 512 + threadIdx.x;
    int b = i >> 8, bo = (i & 255) * 4;
    *(u32*)swz(p0, b, bo) = w[it];
  }
}

// ---------------- per-launch fills (plain stores; flushed at kernel boundary)
__global__ __launch_bounds__(256) void k_fill(u64* __restrict__ p, int n) {
  int i = blockIdx.x * 256 + threadIdx.x;
  if (i < n) p[i] = SENT64;
}
__global__ __launch_bounds__(256) void k_fillf(u32* __restrict__ p, int n) {
  int i = blockIdx.x * 256 + threadIdx.x;
  if (i < n) p[i] = NANW;
}

// ---------------- transpose + f32->bf16 (+ optional gate-interleave col perm)
__global__ __launch_bounds__(256) void k_transcvt(const float* __restrict__ in,
                                                  short* __restrict__ out,
                                                  int R, int N, int perm) {
  __shared__ float tile[32][33];
  int nb = blockIdx.x * 32, rb = blockIdx.y * 32;
  int tx = threadIdx.x & 31, ty = threadIdx.x >> 5;
  for (int i = 0; i < 4; ++i) {
    int r = rb + ty + i * 8;
    int n = nb + tx;
    tile[ty + i * 8][tx] = (n < N) ? in[(size_t)r * N + n] : 0.0f;
  }
  __syncthreads();
  for (int i = 0; i < 4; ++i) {
    int n = nb + ty + i * 8;
    int orow = perm ? (((n & 511) << 2) | (n >> 9)) : n;
    out[(size_t)orow * R + rb + tx] = f2bf(tile[tx][ty + i * 8]);
  }
}

// ---------------- embedding gather -> x_bf [T*B, D] bf16
__global__ __launch_bounds__(256) void k_gather(const int* __restrict__ tokens,
                                                const float* __restrict__ emb,
                                                short* __restrict__ xbf) {
  int row = blockIdx.x;                 // t*16+b
  int t = row >> 4, b = row & 15;
  int tok = tokens[b * Tq + t];
  xbf[(size_t)row * Dq + threadIdx.x] = f2bf(emb[(size_t)tok * Dq + threadIdx.x]);
}

// ---------------- bf16 MFMA GEMM: C[M,ldc] = A[M,K] @ BT[Npad,K]^T + bias
__global__ __launch_bounds__(256) void k_gemm(const short* __restrict__ A,
                                              const short* __restrict__ BT,
                                              float* __restrict__ C,
                                              const float* __restrict__ bias,
                                              int M, int Nreal, int K, int ldc,
                                              int permb) {
  __shared__ short lA[128 * 64];
  __shared__ short lB[128 * 64];
  const int tid = threadIdx.x;
  const int wave = tid >> 6, lane = tid & 63;
  const int l15 = lane & 15, l4 = lane >> 4;
  const int m0 = blockIdx.y * 128, n0 = blockIdx.x * 128;
  const int wm = (wave >> 1) * 64, wn = (wave & 1) * 64;
  facc acc[4][4] = {};

  for (int k0 = 0; k0 < K; k0 += 64) {
    __syncthreads();
    for (int i = 0; i < 4; ++i) {
      int c = i * 256 + wave * 64 + lane;
      int r = c >> 3, q = c & 7;
      int qs = q ^ (r & 7);
      const short* ga = A + (size_t)(m0 + r) * K + k0 + qs * 8;
      const short* gb = BT + (size_t)(n0 + r) * K + k0 + qs * 8;
      short* la = lA + (size_t)(i * 256 + wave * 64) * 8;
      short* lb = lB + (size_t)(i * 256 + wave * 64) * 8;
      __builtin_amdgcn_global_load_lds((const __attribute__((address_space(1))) u32*)ga,
                                       (__attribute__((address_space(3))) u32*)la, 16, 0, 0);
      __builtin_amdgcn_global_load_lds((const __attribute__((address_space(1))) u32*)gb,
                                       (__attribute__((address_space(3))) u32*)lb, 16, 0, 0);
    }
    __syncthreads();
    for (int ks = 0; ks < 2; ++ks) {
      bfrag a[4], b[4];
      for (int mi = 0; mi < 4; ++mi) {
        int r = wm + mi * 16 + l15;
        int qs = (ks * 4 + l4) ^ (r & 7);
        a[mi] = *(const bfrag*)&lA[r * 64 + qs * 8];
      }
      for (int ni = 0; ni < 4; ++ni) {
        int r = wn + ni * 16 + l15;
        int qs = (ks * 4 + l4) ^ (r & 7);
        b[ni] = *(const bfrag*)&lB[r * 64 + qs * 8];
      }
      for (int mi = 0; mi < 4; ++mi)
        for (int ni = 0; ni < 4; ++ni)
          acc[mi][ni] = __builtin_amdgcn_mfma_f32_16x16x32_bf16(a[mi], b[ni], acc[mi][ni], 0, 0, 0);
    }
  }
  for (int ni = 0; ni < 4; ++ni) {
    int col = n0 + wn + ni * 16 + l15;
    if (col >= Nreal) continue;
    int bcol = permb ? (((col & 3) << 9) | (col >> 2)) : col;
    float bs = bias ? bias[bcol] : 0.0f;
    for (int mi = 0; mi < 4; ++mi) {
      int rb = m0 + wm + mi * 16 + l4 * 4;
      facc v = acc[mi][ni];
      C[(size_t)(rb + 0) * ldc + col] = v[0] + bs;
      C[(size_t)(rb + 1) * ldc + col] = v[1] + bs;
      C[(size_t)(rb + 2) * ldc + col] = v[2] + bs;
      C[(size_t)(rb + 3) * ldc + col] = v[3] + bs;
    }
  }
}

// ---------------- mega recurrence: 4 dataflow groups of 32 blocks each.
// grp0=enc1, grp1=enc2, grp2=decA, grp3=decB. Sentinel-slot dataflow (round-5
// proven). Depth ~258 phases vs 385 sequential.
// h circles: u64 [129 slots][4096]. x pipes: u32 [128 slots][4096] (full plane).
// Finals: f32 NaN-sentinel words. Combined own+input poll = one IC hop/phase.
__global__ __launch_bounds__(512, 1) void k_mega(
    const float* __restrict__ XW,
    const short* __restrict__ U1T, const short* __restrict__ U2T,
    const short* __restrict__ W2T, const short* __restrict__ Ud1T,
    const short* __restrict__ Wd1T, const short* __restrict__ Ud2T,
    const short* __restrict__ Wd2T,
    const float* __restrict__ b2, const float* __restrict__ bd1,
    const float* __restrict__ bd2,
    u64* __restrict__ h1buf, u64* __restrict__ h2buf,
    u64* __restrict__ hAbuf, u64* __restrict__ hBbuf,
    u32* __restrict__ xs1, u32* __restrict__ xs2,
    u32* __restrict__ h1f, u32* __restrict__ c1f,
    u32* __restrict__ h2f, u32* __restrict__ c2f,
    short* __restrict__ seq2_bf, short* __restrict__ hBseq_bf,
    short* __restrict__ dec_bf)
{
  __shared__ short pl[4][16][520];     // own-h hi/lo, input hi(/lo)
  __shared__ float zt[8][16][20];
  const int grp  = blockIdx.x >> 5;
  const int rank = blockIdx.x & 31;
  const int tid = threadIdx.x;
  const int wv = tid >> 6, lane = tid & 63;
  const int l15 = lane & 15, l4 = lane >> 4;
  const int kh = wv >> 2;
  const int gw = rank * 4 + (wv & 3);
  const int bb = lane >> 2, jj = lane & 3;
  const int hidx = gw * 4 + jj;
  const int idx = bb * Hq + hidx;
  const int pi = idx >> 1;

  const short* urs = (grp == 0) ? U1T : (grp == 1) ? U2T : (grp == 2) ? Ud1T : Ud2T;
  const short* wrs = (grp == 1) ? W2T : (grp == 2) ? Wd1T : (grp == 3) ? Wd2T : U1T;
  const float* bias = (grp == 1) ? b2 : (grp == 2) ? bd1 : bd2;
  u64* own = (grp == 0) ? h1buf : (grp == 1) ? h2buf : (grp == 2) ? hAbuf : hBbuf;
  const u32* xin = (grp == 1) ? xs1 : xs2;
  u32* xout = (grp == 0) ? xs1 : (grp == 1) ? xs2 : nullptr;

  bfrag ur[8], wr[8];                  // weights in VGPRs (2 mats = 64 VGPR)
  {
    size_t ro = (size_t)(gw * 16 + l15) * Hq + kh * 256 + l4 * 8;
    #pragma unroll
    for (int ks = 0; ks < 8; ++ks) {
      ur[ks] = *(const bfrag*)&urs[ro + ks * 32];
      wr[ks] = *(const bfrag*)&wrs[ro + ks * 32];   // unused by grp0 (valid mem)
    }
  }
  float bi = 0, bf_ = 0, bg_ = 0, bo_ = 0;
  if (grp != 0 && wv < 4) {
    bi = bias[hidx]; bf_ = bias[Hq + hidx];
    bg_ = bias[2 * Hq + hidx]; bo_ = bias[3 * Hq + hidx];
  }
  float c = 0.0f;
  if (wv < 4) {
    float hv = 0.0f;
    if (grp != 0) {                    // carry init from upstream finals (poll)
      const u32* hf = (grp == 3) ? h2f : h1f;
      const u32* cf = (grp == 3) ? c2f : c1f;
      u32 hw = NANW, cw = NANW;
      for (int spin = 0; spin < SPINCAP; ++spin) {
        hw = ic_load32(&hf[idx]); cw = ic_load32(&cf[idx]);
        if (hw != NANW && cw != NANW) break;
        __builtin_amdgcn_s_sleep(16);  // long sleep: don't hammer IC while waiting
      }
      hv = asf(hw); c = asf(cw);
    }
    int hi_ = (int)(unsigned short)f2bf(hv);
    int lo_ = (int)(unsigned short)f2bf(hv - bf2f((short)hi_));
    int hi2 = __shfl_xor(hi_, 1), lo2 = __shfl_xor(lo_, 1);
    if ((jj & 1) == 0) {
      u64 v = (u64)((u32)hi_ | ((u32)hi2 << 16)) | ((u64)((u32)lo_ | ((u32)lo2 << 16)) << 32);
      ic_store64(&own[pi], v);         // slot 0 = initial state
    }
  }

  for (int s = 0; s < Tq; ++s) {
    f32x4 xg = {};
    if (grp == 0 && wv < 4)
      xg = *(const f32x4*)&XW[(size_t)(s * Bq + bb) * G4H + hidx * 4];

    // ---- combined dataflow poll: own slot s (+ input) in ONE retry sweep
    u64 v[8], vx[8];
    u32 w[8];
    const u64* ph = own + (size_t)s * 4096 + tid;
    if (grp == 0) {
      for (int spin = 0;; ++spin) {
        #pragma unroll
        for (int it = 0; it < 8; ++it) v[it] = ic_load64(&ph[it * 512]);
        u32 bad = 0;
        #pragma unroll
        for (int it = 0; it < 8; ++it) bad |= (((u32)v[it] & 0xFFFFu) == SENTW);
        if (!bad || spin >= SPINCAP) break;
        __builtin_amdgcn_s_sleep(1);
      }
    } else if (grp != 3) {
      const u32* px = xin + (size_t)s * 4096 + tid;
      for (int spin = 0;; ++spin) {
        #pragma unroll
        for (int it = 0; it < 8; ++it) v[it] = ic_load64(&ph[it * 512]);
        #pragma unroll
        for (int it = 0; it < 8; ++it) w[it] = ic_load32(&px[it * 512]);
        u32 bad = 0;
        #pragma unroll
        for (int it = 0; it < 8; ++it) {
          bad |= (((u32)v[it] & 0xFFFFu) == SENTW);
          bad |= ((w[it] & 0xFFFFu) == SENTW);
        }
        if (!bad || spin >= SPINCAP) break;
        __builtin_amdgcn_s_sleep(1);
      }
    } else {
      const u64* pa = hAbuf + (size_t)(s + 1) * 4096 + tid;
      for (int spin = 0;; ++spin) {
        #pragma unroll
        for (int it = 0; it < 8; ++it) v[it]  = ic_load64(&ph[it * 512]);
        #pragma unroll
        for (int it = 0; it < 8; ++it) vx[it] = ic_load64(&pa[it * 512]);
        u32 bad = 0;
        #pragma unroll
        for (int it = 0; it < 8; ++it) {
          bad |= (((u32)v[it]  & 0xFFFFu) == SENTW);
          bad |= (((u32)vx[it] & 0xFFFFu) == SENTW);
        }
        if (!bad || spin >= SPINCAP) break;
        __builtin_amdgcn_s_sleep(1);
      }
    }
    stage_h(&pl[0][0][0], &pl[1][0][0], v);
    if (grp == 1 || grp == 2) stage_x(&pl[2][0][0], w);
    else if (grp == 3)        stage_h(&pl[2][0][0], &pl[3][0][0], vx);
    __syncthreads();

    facc a0 = {}, a1 = {}, a2 = {}, a3 = {};
    #pragma unroll
    for (int ks = 0; ks < 8; ++ks) {
      int bo = kh * 512 + ks * 64 + l4 * 16;
      bfrag hh = *(const bfrag*)swz(&pl[0][0][0], l15, bo);
      bfrag hl = *(const bfrag*)swz(&pl[1][0][0], l15, bo);
      a0 = __builtin_amdgcn_mfma_f32_16x16x32_bf16(hh, ur[ks], a0, 0, 0, 0);
      a1 = __builtin_amdgcn_mfma_f32_16x16x32_bf16(hl, ur[ks], a1, 0, 0, 0);
      if (grp == 1 || grp == 2) {
        bfrag xh = *(const bfrag*)swz(&pl[2][0][0], l15, bo);
        a2 = __builtin_amdgcn_mfma_f32_16x16x32_bf16(xh, wr[ks], a2, 0, 0, 0);
      } else if (grp == 3) {
        bfrag xh = *(const bfrag*)swz(&pl[2][0][0], l15, bo);
        bfrag xl = *(const bfrag*)swz(&pl[3][0][0], l15, bo);
        a2 = __builtin_amdgcn_mfma_f32_16x16x32_bf16(xh, wr[ks], a2, 0, 0, 0);
        a3 = __builtin_amdgcn_mfma_f32_16x16x32_bf16(xl, wr[ks], a3, 0, 0, 0);
      }
    }
    a0 += a1;
    if (grp != 0) a0 += a2;
    if (grp == 3) a0 += a3;
    *(f32x4*)&zt[wv][l15][l4 * 4] = a0;
    __syncthreads();

    if (wv < 4) {
      float zi = zt[wv][4 * jj + 0][bb] + zt[wv + 4][4 * jj + 0][bb];
      float zf = zt[wv][4 * jj + 1][bb] + zt[wv + 4][4 * jj + 1][bb];
      float zg = zt[wv][4 * jj + 2][bb] + zt[wv + 4][4 * jj + 2][bb];
      float zo = zt[wv][4 * jj + 3][bb] + zt[wv + 4][4 * jj + 3][bb];
      if (grp == 0) { zi += xg[0]; zf += xg[1]; zg += xg[2]; zo += xg[3]; }
      else          { zi += bi;    zf += bf_;   zg += bg_;   zo += bo_;  }
      c = sigm(zf) * c + sigm(zi) * tanhf(zg);
      float hN = sigm(zo) * tanhf(c);
      int hi_ = (int)(unsigned short)f2bf(hN);
      int lo_ = (int)(unsigned short)f2bf(hN - bf2f((short)hi_));
      int hi2 = __shfl_xor(hi_, 1), lo2 = __shfl_xor(lo_, 1);
      if ((jj & 1) == 0) {
        u64 pv = (u64)((u32)hi_ | ((u32)hi2 << 16)) | ((u64)((u32)lo_ | ((u32)lo2 << 16)) << 32);
        ic_store64(&own[(size_t)(s + 1) * 4096 + pi], pv);
        if (xout) ic_store32(&xout[(size_t)s * 4096 + pi], (u32)pv);
      }
      if (grp == 1) seq2_bf[(size_t)(s * Bq + bb) * Hq + hidx] = (short)hi_;
      if (grp == 3) {
        hBseq_bf[(size_t)(s * Bq + bb) * Hq + hidx] = (short)hi_;
        dec_bf[((size_t)bb * Tq + s) * (2 * Hq) + hidx] = (short)hi_;
      }
      if (s == Tq - 1) {
        if (grp == 0) { ic_store32(&h1f[idx], fbits(hN)); ic_store32(&c1f[idx], fbits(c)); }
        if (grp == 1) { ic_store32(&h2f[idx], fbits(hN)); ic_store32(&c2f[idx], fbits(c)); }
      }
    }
  }
}

// ---------------- batched attention over full seq2 (bf16 in/out; one block per (b,t))
__global__ __launch_bounds__(256) void k_attn(const short* __restrict__ seq2b,
                                              const short* __restrict__ hqb,
                                              short* __restrict__ decb) {
  int blk = blockIdx.x;
  int b = blk >> 7, t = blk & 127;
  __shared__ u32 q[256];         // 512 bf16 packed
  __shared__ float part[256];
  __shared__ float p[Tq];
  int tid = threadIdx.x;
  q[tid] = *(const u32*)&hqb[(size_t)(t * Bq + b) * Hq + tid * 2];
  __syncthreads();
  {
    int s = tid >> 1, half = tid & 1;
    const u32* row = (const u32*)&seq2b[(size_t)(s * Bq + b) * Hq + half * 256];
    const u32* qh = q + half * 128;
    float a = 0.0f;
    #pragma unroll 8
    for (int k = 0; k < 128; ++k) {
      u32 r = row[k], qq = qh[k];
      a += asf(r << 16) * asf(qq << 16) + asf(r & 0xFFFF0000u) * asf(qq & 0xFFFF0000u);
    }
    part[tid] = a;
  }
  __syncthreads();
  if (tid < 64) {
    float v0 = part[2 * tid] + part[2 * tid + 1];
    float v1 = part[2 * (tid + 64)] + part[2 * (tid + 64) + 1];
    float mx = fmaxf(v0, v1);
    for (int off = 32; off; off >>= 1) mx = fmaxf(mx, __shfl_xor(mx, off));
    float e0 = __expf(v0 - mx), e1 = __expf(v1 - mx);
    float sm = e0 + e1;
    for (int off = 32; off; off >>= 1) sm += __shfl_xor(sm, off);
    float inv = 1.0f / sm;
    p[tid] = e0 * inv; p[tid + 64] = e1 * inv;
  }
  __syncthreads();
  float c0 = 0.0f, c1 = 0.0f;
  for (int s = 0; s < Tq; ++s) {
    float ps = p[s];
    u32 r = *(const u32*)&seq2b[(size_t)(s * Bq + b) * Hq + tid * 2];
    c0 += ps * asf(r << 16);
    c1 += ps * asf(r & 0xFFFF0000u);
  }
  u32 o = ((u32)(unsigned short)f2bf(c0)) | (((u32)(unsigned short)f2bf(c1)) << 16);
  *(u32*)&decb[(size_t)(b * Tq + t) * (2 * Hq) + Hq + tid * 2] = o;
}

// ---------------- row softmax over VO=32001 (in-place on d_out)
__global__ __launch_bounds__(256) void k_softmax(float* __restrict__ L) {
  int row = blockIdx.x;
  float* p = L + (size_t)row * VO;
  int tid = threadIdx.x;
  float m = -3.0e38f, s = 0.0f;
  for (int i = tid; i < VO; i += 256) {
    float v = p[i];
    float mn = fmaxf(m, v);
    s = s * __expf(m - mn) + __expf(v - mn);
    m = mn;
  }
  __shared__ float sm[256], ss[256];
  sm[tid] = m; ss[tid] = s;
  __syncthreads();
  for (int off = 128; off; off >>= 1) {
    if (tid < off) {
      float m2 = sm[tid + off], s2 = ss[tid + off];
      float mn = fmaxf(sm[tid], m2);
      ss[tid] = ss[tid] * __expf(sm[tid] - mn) + s2 * __expf(m2 - mn);
      sm[tid] = mn;
    }
    __syncthreads();
  }
  float M = sm[0], IS = 1.0f / ss[0];
  for (int i = tid; i < VO; i += 256) {
    p[i] = __expf(p[i] - M) * IS;
  }
}

// =============================================================================
extern "C" void kernel_launch(void* const* d_in, const int* in_sizes, int n_in,
                              void* d_out, int out_size, void* d_ws, size_t ws_size,
                              hipStream_t stream) {
  const int*   tokens = (const int*)d_in[0];
  const float* emb    = (const float*)d_in[1];
  const float* W1     = (const float*)d_in[2];
  const float* U1     = (const float*)d_in[3];
  const float* b1     = (const float*)d_in[4];
  const float* W2     = (const float*)d_in[5];
  const float* U2     = (const float*)d_in[6];
  const float* b2     = (const float*)d_in[7];
  const float* Wd1    = (const float*)d_in[8];
  const float* Ud1    = (const float*)d_in[9];
  const float* bd1    = (const float*)d_in[10];
  const float* Wd2    = (const float*)d_in[11];
  const float* Ud2    = (const float*)d_in[12];
  const float* bd2    = (const float*)d_in[13];
  const float* Wo     = (const float*)d_in[14];
  const float* bo     = (const float*)d_in[15];
  float* out = (float*)d_out;

  size_t off = 0;
  char* base = (char*)d_ws;
  auto alloc = [&](size_t bytes) -> void* {
    void* p = base + off;
    off += (bytes + 255) & ~(size_t)255;
    return p;
  };
  short* x_bf    = (short*)alloc((size_t)MR * Dq * 2);
  short* W1T     = (short*)alloc((size_t)G4H * Dq * 2);
  short* WoT     = (short*)alloc((size_t)NPAD * (2 * Hq) * 2);
  short* U1T     = (short*)alloc((size_t)G4H * Hq * 2);
  short* U2T     = (short*)alloc((size_t)G4H * Hq * 2);
  short* W2T     = (short*)alloc((size_t)G4H * Hq * 2);
  short* Ud1T    = (short*)alloc((size_t)G4H * Hq * 2);
  short* Wd1T    = (short*)alloc((size_t)G4H * Hq * 2);
  short* Ud2T    = (short*)alloc((size_t)G4H * Hq * 2);
  short* Wd2T    = (short*)alloc((size_t)G4H * Hq * 2);
  float* XW      = (float*)alloc((size_t)MR * G4H * 4);
  short* seq2_bf = (short*)alloc((size_t)MR * Hq * 2);
  short* hBseqbf = (short*)alloc((size_t)MR * Hq * 2);
  short* dec_bf  = (short*)alloc((size_t)MR * 2 * Hq * 2);
  // dataflow: 4 h circles (129 slots x 4096 u64) + 2 x pipes (128 slots x 4096 u32)
  u64*   hflow   = (u64*)alloc((size_t)516 * 4096 * 8);
  u32*   xs1     = (u32*)alloc((size_t)128 * 4096 * 4);
  u32*   xs2     = (u32*)alloc((size_t)128 * 4096 * 4);
  u32*   h1f     = (u32*)alloc(BH * 4);
  u32*   c1f     = (u32*)alloc(BH * 4);
  u32*   h2f     = (u32*)alloc(BH * 4);
  u32*   c2f     = (u32*)alloc(BH * 4);
  u64* h1buf = hflow;
  u64* h2buf = hflow + (size_t)129 * 4096;
  u64* hAbuf = hflow + (size_t)258 * 4096;
  u64* hBbuf = hflow + (size_t)387 * 4096;
  (void)ws_size; (void)in_sizes; (void)n_in; (void)out_size;

  // per-launch sentinel reset: hflow + xs1 + xs2 are contiguous 256B-aligned
  // regions -> one u64 fill covers all. (Round-9 bug: count omitted xs2 and
  // under-counted xs1; fixed.)
  {
    int n64 = 516 * 4096 + 2 * (128 * 4096 / 2);   // hflow + both x pipes
    k_fill<<<(n64 + 255) / 256, 256, 0, stream>>>(hflow, n64);
    k_fillf<<<(4 * BH + 255) / 256, 256, 0, stream>>>(h1f, 4 * BH);
  }

  // weight transposes + bf16 conversion (gate-interleave on all recurrent mats)
  k_transcvt<<<dim3(G4H / 32, Dq / 32), 256, 0, stream>>>(W1, W1T, Dq, G4H, 1);
  k_transcvt<<<dim3(G4H / 32, Hq / 32), 256, 0, stream>>>(U1, U1T, Hq, G4H, 1);
  k_transcvt<<<dim3(G4H / 32, Hq / 32), 256, 0, stream>>>(U2, U2T, Hq, G4H, 1);
  k_transcvt<<<dim3(G4H / 32, Hq / 32), 256, 0, stream>>>(W2, W2T, Hq, G4H, 1);
  k_transcvt<<<dim3(G4H / 32, Hq / 32), 256, 0, stream>>>(Ud1, Ud1T, Hq, G4H, 1);
  k_transcvt<<<dim3(G4H / 32, Hq / 32), 256, 0, stream>>>(Wd1, Wd1T, Hq, G4H, 1);
  k_transcvt<<<dim3(G4H / 32, Hq / 32), 256, 0, stream>>>(Ud2, Ud2T, Hq, G4H, 1);
  k_transcvt<<<dim3(G4H / 32, Hq / 32), 256, 0, stream>>>(Wd2, Wd2T, Hq, G4H, 1);
  k_transcvt<<<dim3(NPAD / 32, (2 * Hq) / 32), 256, 0, stream>>>(Wo, WoT, 2 * Hq, VO, 0);

  k_gather<<<MR, 256, 0, stream>>>(tokens, emb, x_bf);

  // enc1's input projection (x @ W1 + b1), gate-interleaved cols
  k_gemm<<<dim3(G4H / 128, MR / 128), 256, 0, stream>>>(x_bf, W1T, XW, b1, MR, G4H, Dq, G4H, 1);

  // all four LSTM cells as concurrent dataflow groups (depth ~258 phases)
  k_mega<<<128, 512, 0, stream>>>(XW, U1T, U2T, W2T, Ud1T, Wd1T, Ud2T, Wd2T,
                                  b2, bd1, bd2,
                                  h1buf, h2buf, hAbuf, hBbuf, xs1, xs2,
                                  h1f, c1f, h2f, c2f,
                                  seq2_bf, hBseqbf, dec_bf);

  // attention + logits + softmax
  k_attn<<<MR, 256, 0, stream>>>(seq2_bf, hBseqbf, dec_bf);
  k_gemm<<<dim3(NPAD / 128, MR / 128), 256, 0, stream>>>(dec_bf, WoT, out, bo, MR, VO, 2 * Hq, VO, 0);
  k_softmax<<<MR, 256, 0, stream>>>(out);
}

// Round 11
// 2411.406 us; speedup vs baseline: 1.0369x; 1.0369x over previous
//
#include <hip/hip_runtime.h>
#include <hip/hip_bf16.h>
#include <math.h>

// Model dims
#define Bq   16
#define Tq   128
#define Hq   512
#define Dq   256
#define G4H  2048            // 4*H
#define MR   2048            // B*T rows
#define VO   32001           // VOUT+1
#define NPAD 32128           // VO padded to multiple of 128
#define BH   (Bq * Hq)       // 8192
#define SENTW 0x7FC0u        // bf16 NaN sentinel (h is bounded, never NaN)
#define SENT64 0x7FC07FC07FC07FC0ull
#define NANW 0x7FC00000u     // f32 NaN sentinel for finals
#define SPINCAP (1 << 20)    // bounded spins: wrong-answer-not-hang on bug

typedef unsigned int u32;
typedef unsigned long long u64;
typedef __attribute__((ext_vector_type(4))) float f32x4;
typedef __attribute__((ext_vector_type(8))) short bfrag;   // 8 x bf16 (4 VGPRs)
typedef __attribute__((ext_vector_type(4))) float facc;    // mfma accumulator

__device__ __forceinline__ float bf2f(short s) {
  union { unsigned u; float f; } v; v.u = ((unsigned)(unsigned short)s) << 16; return v.f;
}
__device__ __forceinline__ short f2bf(float f) {
  union { float f; unsigned u; } v; v.f = f;
  unsigned r = (v.u + 0x7fffu + ((v.u >> 16) & 1u)) >> 16;
  return (short)r;
}
__device__ __forceinline__ float asf(u32 u) {
  union { u32 u; float f; } v; v.u = u; return v.f;
}
__device__ __forceinline__ u32 fbits(float f) {
  union { float f; u32 u; } v; v.f = f; return v.u;
}
__device__ __forceinline__ float sigm(float x) { return 1.0f / (1.0f + expf(-x)); }

__device__ __forceinline__ void ic_store64(u64* p, u64 v) {
  __hip_atomic_store(p, v, __ATOMIC_RELAXED, __HIP_MEMORY_SCOPE_AGENT);
}
__device__ __forceinline__ u64 ic_load64(const u64* p) {
  return __hip_atomic_load(p, __ATOMIC_RELAXED, __HIP_MEMORY_SCOPE_AGENT);
}
__device__ __forceinline__ void ic_store32(u32* p, u32 v) {
  __hip_atomic_store(p, v, __ATOMIC_RELAXED, __HIP_MEMORY_SCOPE_AGENT);
}
__device__ __forceinline__ u32 ic_load32(const u32* p) {
  return __hip_atomic_load(p, __ATOMIC_RELAXED, __HIP_MEMORY_SCOPE_AGENT);
}

// ---- XOR-swizzled LDS addressing for a [16][520]-short plane (row stride 1040B)
__device__ __forceinline__ void* swz(void* plane, int row, int byteoff) {
  return (void*)((char*)plane + row * 1040 + (byteoff ^ ((row & 7) << 4)));
}

// ---- stage helpers (plane = 16 rows x 256 u32)
__device__ __forceinline__ void stage_h(void* p0, void* p1, const u64 v[8]) {
  #pragma unroll
  for (int it = 0; it < 8; ++it) {
    int i = it * 512 + threadIdx.x;
    int b = i >> 8, bo = (i & 255) * 4;
    *(u32*)swz(p0, b, bo) = (u32)v[it];
    *(u32*)swz(p1, b, bo) = (u32)(v[it] >> 32);
  }
}
__device__ __forceinline__ void stage_x(void* p0, const u32 w[8]) {
  #pragma unroll
  for (int it = 0; it < 8; ++it) {
    int i = it * 512 + threadIdx.x;
    int b = i >> 8, bo = (i & 255) * 4;
    *(u32*)swz(p0, b, bo) = w[it];
  }
}

// ---------------- per-launch fills (plain stores; flushed at kernel boundary)
__global__ __launch_bounds__(256) void k_fill(u64* __restrict__ p, int n) {
  int i = blockIdx.x * 256 + threadIdx.x;
  if (i < n) p[i] = SENT64;
}
__global__ __launch_bounds__(256) void k_fillf(u32* __restrict__ p, int n) {
  int i = blockIdx.x * 256 + threadIdx.x;
  if (i < n) p[i] = NANW;
}

// ---------------- transpose + f32->bf16 (+ optional gate-interleave col perm)
__global__ __launch_bounds__(256) void k_transcvt(const float* __restrict__ in,
                                                  short* __restrict__ out,
                                                  int R, int N, int perm) {
  __shared__ float tile[32][33];
  int nb = blockIdx.x * 32, rb = blockIdx.y * 32;
  int tx = threadIdx.x & 31, ty = threadIdx.x >> 5;
  for (int i = 0; i < 4; ++i) {
    int r = rb + ty + i * 8;
    int n = nb + tx;
    tile[ty + i * 8][tx] = (n < N) ? in[(size_t)r * N + n] : 0.0f;
  }
  __syncthreads();
  for (int i = 0; i < 4; ++i) {
    int n = nb + ty + i * 8;
    int orow = perm ? (((n & 511) << 2) | (n >> 9)) : n;
    out[(size_t)orow * R + rb + tx] = f2bf(tile[tx][ty + i * 8]);
  }
}

// ---------------- embedding gather -> x_bf [T*B, D] bf16
__global__ __launch_bounds__(256) void k_gather(const int* __restrict__ tokens,
                                                const float* __restrict__ emb,
                                                short* __restrict__ xbf) {
  int row = blockIdx.x;                 // t*16+b
  int t = row >> 4, b = row & 15;
  int tok = tokens[b * Tq + t];
  xbf[(size_t)row * Dq + threadIdx.x] = f2bf(emb[(size_t)tok * Dq + threadIdx.x]);
}

// ---------------- bf16 MFMA GEMM: C[M,ldc] = A[M,K] @ BT[Npad,K]^T + bias
__global__ __launch_bounds__(256) void k_gemm(const short* __restrict__ A,
                                              const short* __restrict__ BT,
                                              float* __restrict__ C,
                                              const float* __restrict__ bias,
                                              int M, int Nreal, int K, int ldc,
                                              int permb) {
  __shared__ short lA[128 * 64];
  __shared__ short lB[128 * 64];
  const int tid = threadIdx.x;
  const int wave = tid >> 6, lane = tid & 63;
  const int l15 = lane & 15, l4 = lane >> 4;
  const int m0 = blockIdx.y * 128, n0 = blockIdx.x * 128;
  const int wm = (wave >> 1) * 64, wn = (wave & 1) * 64;
  facc acc[4][4] = {};

  for (int k0 = 0; k0 < K; k0 += 64) {
    __syncthreads();
    for (int i = 0; i < 4; ++i) {
      int c = i * 256 + wave * 64 + lane;
      int r = c >> 3, q = c & 7;
      int qs = q ^ (r & 7);
      const short* ga = A + (size_t)(m0 + r) * K + k0 + qs * 8;
      const short* gb = BT + (size_t)(n0 + r) * K + k0 + qs * 8;
      short* la = lA + (size_t)(i * 256 + wave * 64) * 8;
      short* lb = lB + (size_t)(i * 256 + wave * 64) * 8;
      __builtin_amdgcn_global_load_lds((const __attribute__((address_space(1))) u32*)ga,
                                       (__attribute__((address_space(3))) u32*)la, 16, 0, 0);
      __builtin_amdgcn_global_load_lds((const __attribute__((address_space(1))) u32*)gb,
                                       (__attribute__((address_space(3))) u32*)lb, 16, 0, 0);
    }
    __syncthreads();
    for (int ks = 0; ks < 2; ++ks) {
      bfrag a[4], b[4];
      for (int mi = 0; mi < 4; ++mi) {
        int r = wm + mi * 16 + l15;
        int qs = (ks * 4 + l4) ^ (r & 7);
        a[mi] = *(const bfrag*)&lA[r * 64 + qs * 8];
      }
      for (int ni = 0; ni < 4; ++ni) {
        int r = wn + ni * 16 + l15;
        int qs = (ks * 4 + l4) ^ (r & 7);
        b[ni] = *(const bfrag*)&lB[r * 64 + qs * 8];
      }
      for (int mi = 0; mi < 4; ++mi)
        for (int ni = 0; ni < 4; ++ni)
          acc[mi][ni] = __builtin_amdgcn_mfma_f32_16x16x32_bf16(a[mi], b[ni], acc[mi][ni], 0, 0, 0);
    }
  }
  for (int ni = 0; ni < 4; ++ni) {
    int col = n0 + wn + ni * 16 + l15;
    if (col >= Nreal) continue;
    int bcol = permb ? (((col & 3) << 9) | (col >> 2)) : col;
    float bs = bias ? bias[bcol] : 0.0f;
    for (int mi = 0; mi < 4; ++mi) {
      int rb = m0 + wm + mi * 16 + l4 * 4;
      facc v = acc[mi][ni];
      C[(size_t)(rb + 0) * ldc + col] = v[0] + bs;
      C[(size_t)(rb + 1) * ldc + col] = v[1] + bs;
      C[(size_t)(rb + 2) * ldc + col] = v[2] + bs;
      C[(size_t)(rb + 3) * ldc + col] = v[3] + bs;
    }
  }
}

// ---------------- mega recurrence: 4 dataflow groups of 32 blocks each.
// grp0=enc1, grp1=enc2, grp2=decA, grp3=decB. Critical path = 384 cell-steps
// (enc2/decB carries are upstream FINALS); decA free-rides alongside enc2.
// Round-10 lesson: idle groups' waves 4-7 entered the main poll immediately
// (the carry gate only covered wv<4) and their 64KB sweeps saturated the IC,
// inflating every phase 2.6 -> 5us. Fix: __syncthreads() gate after carry-init
// so waiting groups touch only the 32KB finals arrays with long backoff.
__global__ __launch_bounds__(512, 1) void k_mega(
    const float* __restrict__ XW,
    const short* __restrict__ U1T, const short* __restrict__ U2T,
    const short* __restrict__ W2T, const short* __restrict__ Ud1T,
    const short* __restrict__ Wd1T, const short* __restrict__ Ud2T,
    const short* __restrict__ Wd2T,
    const float* __restrict__ b2, const float* __restrict__ bd1,
    const float* __restrict__ bd2,
    u64* __restrict__ h1buf, u64* __restrict__ h2buf,
    u64* __restrict__ hAbuf, u64* __restrict__ hBbuf,
    u32* __restrict__ xs1, u32* __restrict__ xs2,
    u32* __restrict__ h1f, u32* __restrict__ c1f,
    u32* __restrict__ h2f, u32* __restrict__ c2f,
    short* __restrict__ seq2_bf, short* __restrict__ hBseq_bf,
    short* __restrict__ dec_bf)
{
  __shared__ short pl[4][16][520];     // own-h hi/lo, input hi(/lo)
  __shared__ float zt[8][16][20];
  const int grp  = blockIdx.x >> 5;
  const int rank = blockIdx.x & 31;
  const int tid = threadIdx.x;
  const int wv = tid >> 6, lane = tid & 63;
  const int l15 = lane & 15, l4 = lane >> 4;
  const int kh = wv >> 2;
  const int gw = rank * 4 + (wv & 3);
  const int bb = lane >> 2, jj = lane & 3;
  const int hidx = gw * 4 + jj;
  const int idx = bb * Hq + hidx;
  const int pi = idx >> 1;

  const short* urs = (grp == 0) ? U1T : (grp == 1) ? U2T : (grp == 2) ? Ud1T : Ud2T;
  const short* wrs = (grp == 1) ? W2T : (grp == 2) ? Wd1T : (grp == 3) ? Wd2T : U1T;
  const float* bias = (grp == 1) ? b2 : (grp == 2) ? bd1 : bd2;
  u64* own = (grp == 0) ? h1buf : (grp == 1) ? h2buf : (grp == 2) ? hAbuf : hBbuf;
  const u32* xin = (grp == 1) ? xs1 : xs2;
  u32* xout = (grp == 0) ? xs1 : (grp == 1) ? xs2 : nullptr;

  bfrag ur[8], wr[8];                  // weights in VGPRs (2 mats = 64 VGPR)
  {
    size_t ro = (size_t)(gw * 16 + l15) * Hq + kh * 256 + l4 * 8;
    #pragma unroll
    for (int ks = 0; ks < 8; ++ks) {
      ur[ks] = *(const bfrag*)&urs[ro + ks * 32];
      wr[ks] = *(const bfrag*)&wrs[ro + ks * 32];   // unused by grp0 (valid mem)
    }
  }
  float bi = 0, bf_ = 0, bg_ = 0, bo_ = 0;
  if (grp != 0 && wv < 4) {
    bi = bias[hidx]; bf_ = bias[Hq + hidx];
    bg_ = bias[2 * Hq + hidx]; bo_ = bias[3 * Hq + hidx];
  }
  float c = 0.0f;
  if (wv < 4) {
    float hv = 0.0f;
    if (grp != 0) {                    // carry-gate: poll ONLY the tiny finals
      const u32* hf = (grp == 3) ? h2f : h1f;
      const u32* cf = (grp == 3) ? c2f : c1f;
      u32 hw = NANW, cw = NANW;
      for (int spin = 0; spin < SPINCAP; ++spin) {
        hw = ic_load32(&hf[idx]); cw = ic_load32(&cf[idx]);
        if (hw != NANW && cw != NANW) break;
        __builtin_amdgcn_s_sleep(32);  // long backoff: ~1.3us between IC touches
      }
      hv = asf(hw); c = asf(cw);
    }
    int hi_ = (int)(unsigned short)f2bf(hv);
    int lo_ = (int)(unsigned short)f2bf(hv - bf2f((short)hi_));
    int hi2 = __shfl_xor(hi_, 1), lo2 = __shfl_xor(lo_, 1);
    if ((jj & 1) == 0) {
      u64 v = (u64)((u32)hi_ | ((u32)hi2 << 16)) | ((u64)((u32)lo_ | ((u32)lo2 << 16)) << 32);
      ic_store64(&own[pi], v);         // slot 0 = initial state
    }
  }
  __syncthreads();   // GATE: waves 4-7 must not enter the main poll until the
                     // carry is ready (round-10 contention bug)

  for (int s = 0; s < Tq; ++s) {
    f32x4 xg = {};
    if (grp == 0 && wv < 4)
      xg = *(const f32x4*)&XW[(size_t)(s * Bq + bb) * G4H + hidx * 4];

    // ---- combined dataflow poll: own slot s (+ input) in ONE retry sweep
    u64 v[8], vx[8];
    u32 w[8];
    const u64* ph = own + (size_t)s * 4096 + tid;
    if (grp == 0) {
      for (int spin = 0;; ++spin) {
        #pragma unroll
        for (int it = 0; it < 8; ++it) v[it] = ic_load64(&ph[it * 512]);
        u32 bad = 0;
        #pragma unroll
        for (int it = 0; it < 8; ++it) bad |= (((u32)v[it] & 0xFFFFu) == SENTW);
        if (!bad || spin >= SPINCAP) break;
        __builtin_amdgcn_s_sleep(1);
      }
    } else if (grp != 3) {
      const u32* px = xin + (size_t)s * 4096 + tid;
      for (int spin = 0;; ++spin) {
        #pragma unroll
        for (int it = 0; it < 8; ++it) v[it] = ic_load64(&ph[it * 512]);
        #pragma unroll
        for (int it = 0; it < 8; ++it) w[it] = ic_load32(&px[it * 512]);
        u32 bad = 0;
        #pragma unroll
        for (int it = 0; it < 8; ++it) {
          bad |= (((u32)v[it] & 0xFFFFu) == SENTW);
          bad |= ((w[it] & 0xFFFFu) == SENTW);
        }
        if (!bad || spin >= SPINCAP) break;
        __builtin_amdgcn_s_sleep(1);
      }
    } else {
      const u64* pa = hAbuf + (size_t)(s + 1) * 4096 + tid;
      for (int spin = 0;; ++spin) {
        #pragma unroll
        for (int it = 0; it < 8; ++it) v[it]  = ic_load64(&ph[it * 512]);
        #pragma unroll
        for (int it = 0; it < 8; ++it) vx[it] = ic_load64(&pa[it * 512]);
        u32 bad = 0;
        #pragma unroll
        for (int it = 0; it < 8; ++it) {
          bad |= (((u32)v[it]  & 0xFFFFu) == SENTW);
          bad |= (((u32)vx[it] & 0xFFFFu) == SENTW);
        }
        if (!bad || spin >= SPINCAP) break;
        __builtin_amdgcn_s_sleep(1);
      }
    }
    stage_h(&pl[0][0][0], &pl[1][0][0], v);
    if (grp == 1 || grp == 2) stage_x(&pl[2][0][0], w);
    else if (grp == 3)        stage_h(&pl[2][0][0], &pl[3][0][0], vx);
    __syncthreads();

    facc a0 = {}, a1 = {}, a2 = {}, a3 = {};
    #pragma unroll
    for (int ks = 0; ks < 8; ++ks) {
      int bo = kh * 512 + ks * 64 + l4 * 16;
      bfrag hh = *(const bfrag*)swz(&pl[0][0][0], l15, bo);
      bfrag hl = *(const bfrag*)swz(&pl[1][0][0], l15, bo);
      a0 = __builtin_amdgcn_mfma_f32_16x16x32_bf16(hh, ur[ks], a0, 0, 0, 0);
      a1 = __builtin_amdgcn_mfma_f32_16x16x32_bf16(hl, ur[ks], a1, 0, 0, 0);
      if (grp == 1 || grp == 2) {
        bfrag xh = *(const bfrag*)swz(&pl[2][0][0], l15, bo);
        a2 = __builtin_amdgcn_mfma_f32_16x16x32_bf16(xh, wr[ks], a2, 0, 0, 0);
      } else if (grp == 3) {
        bfrag xh = *(const bfrag*)swz(&pl[2][0][0], l15, bo);
        bfrag xl = *(const bfrag*)swz(&pl[3][0][0], l15, bo);
        a2 = __builtin_amdgcn_mfma_f32_16x16x32_bf16(xh, wr[ks], a2, 0, 0, 0);
        a3 = __builtin_amdgcn_mfma_f32_16x16x32_bf16(xl, wr[ks], a3, 0, 0, 0);
      }
    }
    a0 += a1;
    if (grp != 0) a0 += a2;
    if (grp == 3) a0 += a3;
    *(f32x4*)&zt[wv][l15][l4 * 4] = a0;
    __syncthreads();

    if (wv < 4) {
      float zi = zt[wv][4 * jj + 0][bb] + zt[wv + 4][4 * jj + 0][bb];
      float zf = zt[wv][4 * jj + 1][bb] + zt[wv + 4][4 * jj + 1][bb];
      float zg = zt[wv][4 * jj + 2][bb] + zt[wv + 4][4 * jj + 2][bb];
      float zo = zt[wv][4 * jj + 3][bb] + zt[wv + 4][4 * jj + 3][bb];
      if (grp == 0) { zi += xg[0]; zf += xg[1]; zg += xg[2]; zo += xg[3]; }
      else          { zi += bi;    zf += bf_;   zg += bg_;   zo += bo_;  }
      c = sigm(zf) * c + sigm(zi) * tanhf(zg);
      float hN = sigm(zo) * tanhf(c);
      int hi_ = (int)(unsigned short)f2bf(hN);
      int lo_ = (int)(unsigned short)f2bf(hN - bf2f((short)hi_));
      int hi2 = __shfl_xor(hi_, 1), lo2 = __shfl_xor(lo_, 1);
      if ((jj & 1) == 0) {
        u64 pv = (u64)((u32)hi_ | ((u32)hi2 << 16)) | ((u64)((u32)lo_ | ((u32)lo2 << 16)) << 32);
        ic_store64(&own[(size_t)(s + 1) * 4096 + pi], pv);
        if (xout) ic_store32(&xout[(size_t)s * 4096 + pi], (u32)pv);
      }
      if (grp == 1) seq2_bf[(size_t)(s * Bq + bb) * Hq + hidx] = (short)hi_;
      if (grp == 3) {
        hBseq_bf[(size_t)(s * Bq + bb) * Hq + hidx] = (short)hi_;
        dec_bf[((size_t)bb * Tq + s) * (2 * Hq) + hidx] = (short)hi_;
      }
      if (s == Tq - 1) {
        if (grp == 0) { ic_store32(&h1f[idx], fbits(hN)); ic_store32(&c1f[idx], fbits(c)); }
        if (grp == 1) { ic_store32(&h2f[idx], fbits(hN)); ic_store32(&c2f[idx], fbits(c)); }
      }
    }
  }
}

// ---------------- batched attention over full seq2 (bf16 in/out; one block per (b,t))
__global__ __launch_bounds__(256) void k_attn(const short* __restrict__ seq2b,
                                              const short* __restrict__ hqb,
                                              short* __restrict__ decb) {
  int blk = blockIdx.x;
  int b = blk >> 7, t = blk & 127;
  __shared__ u32 q[256];         // 512 bf16 packed
  __shared__ float part[256];
  __shared__ float p[Tq];
  int tid = threadIdx.x;
  q[tid] = *(const u32*)&hqb[(size_t)(t * Bq + b) * Hq + tid * 2];
  __syncthreads();
  {
    int s = tid >> 1, half = tid & 1;
    const u32* row = (const u32*)&seq2b[(size_t)(s * Bq + b) * Hq + half * 256];
    const u32* qh = q + half * 128;
    float a = 0.0f;
    #pragma unroll 8
    for (int k = 0; k < 128; ++k) {
      u32 r = row[k], qq = qh[k];
      a += asf(r << 16) * asf(qq << 16) + asf(r & 0xFFFF0000u) * asf(qq & 0xFFFF0000u);
    }
    part[tid] = a;
  }
  __syncthreads();
  if (tid < 64) {
    float v0 = part[2 * tid] + part[2 * tid + 1];
    float v1 = part[2 * (tid + 64)] + part[2 * (tid + 64) + 1];
    float mx = fmaxf(v0, v1);
    for (int off = 32; off; off >>= 1) mx = fmaxf(mx, __shfl_xor(mx, off));
    float e0 = __expf(v0 - mx), e1 = __expf(v1 - mx);
    float sm = e0 + e1;
    for (int off = 32; off; off >>= 1) sm += __shfl_xor(sm, off);
    float inv = 1.0f / sm;
    p[tid] = e0 * inv; p[tid + 64] = e1 * inv;
  }
  __syncthreads();
  float c0 = 0.0f, c1 = 0.0f;
  for (int s = 0; s < Tq; ++s) {
    float ps = p[s];
    u32 r = *(const u32*)&seq2b[(size_t)(s * Bq + b) * Hq + tid * 2];
    c0 += ps * asf(r << 16);
    c1 += ps * asf(r & 0xFFFF0000u);
  }
  u32 o = ((u32)(unsigned short)f2bf(c0)) | (((u32)(unsigned short)f2bf(c1)) << 16);
  *(u32*)&decb[(size_t)(b * Tq + t) * (2 * Hq) + Hq + tid * 2] = o;
}

// ---------------- row softmax over VO=32001 (in-place on d_out)
__global__ __launch_bounds__(256) void k_softmax(float* __restrict__ L) {
  int row = blockIdx.x;
  float* p = L + (size_t)row * VO;
  int tid = threadIdx.x;
  float m = -3.0e38f, s = 0.0f;
  for (int i = tid; i < VO; i += 256) {
    float v = p[i];
    float mn = fmaxf(m, v);
    s = s * __expf(m - mn) + __expf(v - mn);
    m = mn;
  }
  __shared__ float sm[256], ss[256];
  sm[tid] = m; ss[tid] = s;
  __syncthreads();
  for (int off = 128; off; off >>= 1) {
    if (tid < off) {
      float m2 = sm[tid + off], s2 = ss[tid + off];
      float mn = fmaxf(sm[tid], m2);
      ss[tid] = ss[tid] * __expf(sm[tid] - mn) + s2 * __expf(m2 - mn);
      sm[tid] = mn;
    }
    __syncthreads();
  }
  float M = sm[0], IS = 1.0f / ss[0];
  for (int i = tid; i < VO; i += 256) {
    p[i] = __expf(p[i] - M) * IS;
  }
}

// =============================================================================
extern "C" void kernel_launch(void* const* d_in, const int* in_sizes, int n_in,
                              void* d_out, int out_size, void* d_ws, size_t ws_size,
                              hipStream_t stream) {
  const int*   tokens = (const int*)d_in[0];
  const float* emb    = (const float*)d_in[1];
  const float* W1     = (const float*)d_in[2];
  const float* U1     = (const float*)d_in[3];
  const float* b1     = (const float*)d_in[4];
  const float* W2     = (const float*)d_in[5];
  const float* U2     = (const float*)d_in[6];
  const float* b2     = (const float*)d_in[7];
  const float* Wd1    = (const float*)d_in[8];
  const float* Ud1    = (const float*)d_in[9];
  const float* bd1    = (const float*)d_in[10];
  const float* Wd2    = (const float*)d_in[11];
  const float* Ud2    = (const float*)d_in[12];
  const float* bd2    = (const float*)d_in[13];
  const float* Wo     = (const float*)d_in[14];
  const float* bo     = (const float*)d_in[15];
  float* out = (float*)d_out;

  size_t off = 0;
  char* base = (char*)d_ws;
  auto alloc = [&](size_t bytes) -> void* {
    void* p = base + off;
    off += (bytes + 255) & ~(size_t)255;
    return p;
  };
  short* x_bf    = (short*)alloc((size_t)MR * Dq * 2);
  short* W1T     = (short*)alloc((size_t)G4H * Dq * 2);
  short* WoT     = (short*)alloc((size_t)NPAD * (2 * Hq) * 2);
  short* U1T     = (short*)alloc((size_t)G4H * Hq * 2);
  short* U2T     = (short*)alloc((size_t)G4H * Hq * 2);
  short* W2T     = (short*)alloc((size_t)G4H * Hq * 2);
  short* Ud1T    = (short*)alloc((size_t)G4H * Hq * 2);
  short* Wd1T    = (short*)alloc((size_t)G4H * Hq * 2);
  short* Ud2T    = (short*)alloc((size_t)G4H * Hq * 2);
  short* Wd2T    = (short*)alloc((size_t)G4H * Hq * 2);
  float* XW      = (float*)alloc((size_t)MR * G4H * 4);
  short* seq2_bf = (short*)alloc((size_t)MR * Hq * 2);
  short* hBseqbf = (short*)alloc((size_t)MR * Hq * 2);
  short* dec_bf  = (short*)alloc((size_t)MR * 2 * Hq * 2);
  // dataflow: 4 h circles (129 slots x 4096 u64) + 2 x pipes (128 slots x 4096 u32)
  u64*   hflow   = (u64*)alloc((size_t)516 * 4096 * 8);
  u32*   xs1     = (u32*)alloc((size_t)128 * 4096 * 4);
  u32*   xs2     = (u32*)alloc((size_t)128 * 4096 * 4);
  u32*   h1f     = (u32*)alloc(BH * 4);
  u32*   c1f     = (u32*)alloc(BH * 4);
  u32*   h2f     = (u32*)alloc(BH * 4);
  u32*   c2f     = (u32*)alloc(BH * 4);
  u64* h1buf = hflow;
  u64* h2buf = hflow + (size_t)129 * 4096;
  u64* hAbuf = hflow + (size_t)258 * 4096;
  u64* hBbuf = hflow + (size_t)387 * 4096;
  (void)ws_size; (void)in_sizes; (void)n_in; (void)out_size;

  // per-launch sentinel reset: hflow + xs1 + xs2 contiguous -> one u64 fill
  {
    int n64 = 516 * 4096 + 2 * (128 * 4096 / 2);   // hflow + both x pipes
    k_fill<<<(n64 + 255) / 256, 256, 0, stream>>>(hflow, n64);
    k_fillf<<<(4 * BH + 255) / 256, 256, 0, stream>>>(h1f, 4 * BH);
  }

  // weight transposes + bf16 conversion (gate-interleave on all recurrent mats)
  k_transcvt<<<dim3(G4H / 32, Dq / 32), 256, 0, stream>>>(W1, W1T, Dq, G4H, 1);
  k_transcvt<<<dim3(G4H / 32, Hq / 32), 256, 0, stream>>>(U1, U1T, Hq, G4H, 1);
  k_transcvt<<<dim3(G4H / 32, Hq / 32), 256, 0, stream>>>(U2, U2T, Hq, G4H, 1);
  k_transcvt<<<dim3(G4H / 32, Hq / 32), 256, 0, stream>>>(W2, W2T, Hq, G4H, 1);
  k_transcvt<<<dim3(G4H / 32, Hq / 32), 256, 0, stream>>>(Ud1, Ud1T, Hq, G4H, 1);
  k_transcvt<<<dim3(G4H / 32, Hq / 32), 256, 0, stream>>>(Wd1, Wd1T, Hq, G4H, 1);
  k_transcvt<<<dim3(G4H / 32, Hq / 32), 256, 0, stream>>>(Ud2, Ud2T, Hq, G4H, 1);
  k_transcvt<<<dim3(G4H / 32, Hq / 32), 256, 0, stream>>>(Wd2, Wd2T, Hq, G4H, 1);
  k_transcvt<<<dim3(NPAD / 32, (2 * Hq) / 32), 256, 0, stream>>>(Wo, WoT, 2 * Hq, VO, 0);

  k_gather<<<MR, 256, 0, stream>>>(tokens, emb, x_bf);

  // enc1's input projection (x @ W1 + b1), gate-interleaved cols
  k_gemm<<<dim3(G4H / 128, MR / 128), 256, 0, stream>>>(x_bf, W1T, XW, b1, MR, G4H, Dq, G4H, 1);

  // all four LSTM cells as gated dataflow groups
  k_mega<<<128, 512, 0, stream>>>(XW, U1T, U2T, W2T, Ud1T, Wd1T, Ud2T, Wd2T,
                                  b2, bd1, bd2,
                                  h1buf, h2buf, hAbuf, hBbuf, xs1, xs2,
                                  h1f, c1f, h2f, c2f,
                                  seq2_bf, hBseqbf, dec_bf);

  // attention + logits + softmax
  k_attn<<<MR, 256, 0, stream>>>(seq2_bf, hBseqbf, dec_bf);
  k_gemm<<<dim3(NPAD / 128, MR / 128), 256, 0, stream>>>(dec_bf, WoT, out, bo, MR, VO, 2 * Hq, VO, 0);
  k_softmax<<<MR, 256, 0, stream>>>(out);
}

// Round 12
// 2394.713 us; speedup vs baseline: 1.0441x; 1.0070x over previous
//
#include <hip/hip_runtime.h>
#include <hip/hip_bf16.h>
#include <math.h>

// Model dims
#define Bq   16
#define Tq   128
#define Hq   512
#define Dq   256
#define G4H  2048            // 4*H
#define MR   2048            // B*T rows
#define VO   32001           // VOUT+1
#define NPAD 32128           // VO padded to multiple of 128
#define BH   (Bq * Hq)       // 8192
#define SENTW 0x7FC0u        // bf16 NaN sentinel (h is bounded, never NaN)
#define SENT64 0x7FC07FC07FC07FC0ull
#define SPINCAP (1 << 20)    // bounded spins: wrong-answer-not-hang on bug

typedef unsigned int u32;
typedef unsigned long long u64;
typedef __attribute__((ext_vector_type(4))) float f32x4;
typedef __attribute__((ext_vector_type(8))) short bfrag;   // 8 x bf16 (4 VGPRs)
typedef __attribute__((ext_vector_type(4))) float facc;    // mfma accumulator

__device__ __forceinline__ float bf2f(short s) {
  union { unsigned u; float f; } v; v.u = ((unsigned)(unsigned short)s) << 16; return v.f;
}
__device__ __forceinline__ short f2bf(float f) {
  union { float f; unsigned u; } v; v.f = f;
  unsigned r = (v.u + 0x7fffu + ((v.u >> 16) & 1u)) >> 16;
  return (short)r;
}
__device__ __forceinline__ float asf(u32 u) {
  union { u32 u; float f; } v; v.u = u; return v.f;
}
__device__ __forceinline__ float sigm(float x) { return 1.0f / (1.0f + expf(-x)); }

__device__ __forceinline__ void ic_store64(u64* p, u64 v) {
  __hip_atomic_store(p, v, __ATOMIC_RELAXED, __HIP_MEMORY_SCOPE_AGENT);
}
__device__ __forceinline__ u64 ic_load64(const u64* p) {
  return __hip_atomic_load(p, __ATOMIC_RELAXED, __HIP_MEMORY_SCOPE_AGENT);
}

// ---- XOR-swizzled LDS addressing for a [16][520]-short plane (row stride 1040B)
__device__ __forceinline__ void* swz(void* plane, int row, int byteoff) {
  return (void*)((char*)plane + row * 1040 + (byteoff ^ ((row & 7) << 4)));
}

// ---- stage helper (plane pair = hi/lo, 16 rows x 256 u32 each)
__device__ __forceinline__ void stage_h(void* p0, void* p1, const u64 v[8]) {
  #pragma unroll
  for (int it = 0; it < 8; ++it) {
    int i = it * 512 + threadIdx.x;
    int b = i >> 8, bo = (i & 255) * 4;
    *(u32*)swz(p0, b, bo) = (u32)v[it];
    *(u32*)swz(p1, b, bo) = (u32)(v[it] >> 32);
  }
}

// ---------------- per-launch sentinel fill
__global__ __launch_bounds__(256) void k_fill(u64* __restrict__ p, int n) {
  int i = blockIdx.x * 256 + threadIdx.x;
  if (i < n) p[i] = SENT64;
}

// ---------------- transpose + f32->bf16 (+ optional gate-interleave col perm)
__global__ __launch_bounds__(256) void k_transcvt(const float* __restrict__ in,
                                                  short* __restrict__ out,
                                                  int R, int N, int perm) {
  __shared__ float tile[32][33];
  int nb = blockIdx.x * 32, rb = blockIdx.y * 32;
  int tx = threadIdx.x & 31, ty = threadIdx.x >> 5;
  for (int i = 0; i < 4; ++i) {
    int r = rb + ty + i * 8;
    int n = nb + tx;
    tile[ty + i * 8][tx] = (n < N) ? in[(size_t)r * N + n] : 0.0f;
  }
  __syncthreads();
  for (int i = 0; i < 4; ++i) {
    int n = nb + ty + i * 8;
    int orow = perm ? (((n & 511) << 2) | (n >> 9)) : n;
    out[(size_t)orow * R + rb + tx] = f2bf(tile[tx][ty + i * 8]);
  }
}

// ---------------- embedding gather -> x_bf [T*B, D] bf16
__global__ __launch_bounds__(256) void k_gather(const int* __restrict__ tokens,
                                                const float* __restrict__ emb,
                                                short* __restrict__ xbf) {
  int row = blockIdx.x;                 // t*16+b
  int t = row >> 4, b = row & 15;
  int tok = tokens[b * Tq + t];
  xbf[(size_t)row * Dq + threadIdx.x] = f2bf(emb[(size_t)tok * Dq + threadIdx.x]);
}

// ---------------- bf16 MFMA GEMM: C[M,ldc] = A[M,K] @ BT[Npad,K]^T + bias
__global__ __launch_bounds__(256) void k_gemm(const short* __restrict__ A,
                                              const short* __restrict__ BT,
                                              float* __restrict__ C,
                                              const float* __restrict__ bias,
                                              int M, int Nreal, int K, int ldc,
                                              int permb) {
  __shared__ short lA[128 * 64];
  __shared__ short lB[128 * 64];
  const int tid = threadIdx.x;
  const int wave = tid >> 6, lane = tid & 63;
  const int l15 = lane & 15, l4 = lane >> 4;
  const int m0 = blockIdx.y * 128, n0 = blockIdx.x * 128;
  const int wm = (wave >> 1) * 64, wn = (wave & 1) * 64;
  facc acc[4][4] = {};

  for (int k0 = 0; k0 < K; k0 += 64) {
    __syncthreads();
    for (int i = 0; i < 4; ++i) {
      int c = i * 256 + wave * 64 + lane;
      int r = c >> 3, q = c & 7;
      int qs = q ^ (r & 7);
      const short* ga = A + (size_t)(m0 + r) * K + k0 + qs * 8;
      const short* gb = BT + (size_t)(n0 + r) * K + k0 + qs * 8;
      short* la = lA + (size_t)(i * 256 + wave * 64) * 8;
      short* lb = lB + (size_t)(i * 256 + wave * 64) * 8;
      __builtin_amdgcn_global_load_lds((const __attribute__((address_space(1))) u32*)ga,
                                       (__attribute__((address_space(3))) u32*)la, 16, 0, 0);
      __builtin_amdgcn_global_load_lds((const __attribute__((address_space(1))) u32*)gb,
                                       (__attribute__((address_space(3))) u32*)lb, 16, 0, 0);
    }
    __syncthreads();
    for (int ks = 0; ks < 2; ++ks) {
      bfrag a[4], b[4];
      for (int mi = 0; mi < 4; ++mi) {
        int r = wm + mi * 16 + l15;
        int qs = (ks * 4 + l4) ^ (r & 7);
        a[mi] = *(const bfrag*)&lA[r * 64 + qs * 8];
      }
      for (int ni = 0; ni < 4; ++ni) {
        int r = wn + ni * 16 + l15;
        int qs = (ks * 4 + l4) ^ (r & 7);
        b[ni] = *(const bfrag*)&lB[r * 64 + qs * 8];
      }
      for (int mi = 0; mi < 4; ++mi)
        for (int ni = 0; ni < 4; ++ni)
          acc[mi][ni] = __builtin_amdgcn_mfma_f32_16x16x32_bf16(a[mi], b[ni], acc[mi][ni], 0, 0, 0);
    }
  }
  for (int ni = 0; ni < 4; ++ni) {
    int col = n0 + wn + ni * 16 + l15;
    if (col >= Nreal) continue;
    int bcol = permb ? (((col & 3) << 9) | (col >> 2)) : col;
    float bs = bias ? bias[bcol] : 0.0f;
    for (int mi = 0; mi < 4; ++mi) {
      int rb = m0 + wm + mi * 16 + l4 * 4;
      facc v = acc[mi][ni];
      C[(size_t)(rb + 0) * ldc + col] = v[0] + bs;
      C[(size_t)(rb + 1) * ldc + col] = v[1] + bs;
      C[(size_t)(rb + 2) * ldc + col] = v[2] + bs;
      C[(size_t)(rb + 3) * ldc + col] = v[3] + bs;
    }
  }
}

// h circles: u64 [129 slots][4096]; slot s = state consumed at step s; slots
// s+1 stored for ALL s (slot 128 feeds downstream cells as seq input).
// Element pi=(bb*512+col)/2 packs (hi_e|hi_o<<16) | (lo_e|lo_o<<16)<<32.

// ---------------- enc1: single-cell recurrence, XW input (round-5 proven 2.6us/phase)
__global__ __launch_bounds__(512, 1) void k_rec1(const float* __restrict__ XW,
                                                 const short* __restrict__ UT,
                                                 u64* __restrict__ hbuf,
                                                 float* __restrict__ hfin,
                                                 float* __restrict__ cfin) {
  __shared__ short lh[2][16][520];
  __shared__ float zt[8][16][20];
  const int tid = threadIdx.x;
  const int wv = tid >> 6, lane = tid & 63;
  const int l15 = lane & 15, l4 = lane >> 4;
  const int kh = wv >> 2;
  const int gw = blockIdx.x * 4 + (wv & 3);
  const int bb = lane >> 2, jj = lane & 3;
  const int hidx = gw * 4 + jj;

  bfrag ur[8];
  {
    const short* ub = UT + (size_t)(gw * 16 + l15) * Hq + kh * 256 + l4 * 8;
    #pragma unroll
    for (int ks = 0; ks < 8; ++ks) ur[ks] = *(const bfrag*)&ub[ks * 32];
  }
  float c = 0.0f;
  if (wv < 4 && (jj & 1) == 0) {
    ic_store64(&hbuf[(bb * Hq + hidx) >> 1], 0ull);    // h(-1)=0 (hi=lo=0)
  }

  for (int s = 0; s < Tq; ++s) {
    f32x4 xg = {};
    if (wv < 4) xg = *(const f32x4*)&XW[(size_t)(s * Bq + bb) * G4H + hidx * 4];
    const u64* hsrc = hbuf + (size_t)s * 4096 + tid;
    u64 v[8];
    for (int spin = 0;; ++spin) {
      #pragma unroll
      for (int it = 0; it < 8; ++it) v[it] = ic_load64(&hsrc[it * 512]);
      u32 bad = 0;
      #pragma unroll
      for (int it = 0; it < 8; ++it) bad |= (((u32)v[it] & 0xFFFFu) == SENTW);
      if (!bad || spin >= SPINCAP) break;
      __builtin_amdgcn_s_sleep(1);
    }
    stage_h(&lh[0][0][0], &lh[1][0][0], v);
    __syncthreads();
    facc a0 = {}, a1 = {};
    #pragma unroll
    for (int ks = 0; ks < 8; ++ks) {
      int bo = kh * 512 + ks * 64 + l4 * 16;
      bfrag ah = *(const bfrag*)swz(&lh[0][0][0], l15, bo);
      bfrag al = *(const bfrag*)swz(&lh[1][0][0], l15, bo);
      a0 = __builtin_amdgcn_mfma_f32_16x16x32_bf16(ah, ur[ks], a0, 0, 0, 0);
      a1 = __builtin_amdgcn_mfma_f32_16x16x32_bf16(al, ur[ks], a1, 0, 0, 0);
    }
    a0 += a1;
    *(f32x4*)&zt[wv][l15][l4 * 4] = a0;
    __syncthreads();
    if (wv < 4) {
      float zi = zt[wv][4 * jj + 0][bb] + zt[wv + 4][4 * jj + 0][bb] + xg[0];
      float zf = zt[wv][4 * jj + 1][bb] + zt[wv + 4][4 * jj + 1][bb] + xg[1];
      float zg = zt[wv][4 * jj + 2][bb] + zt[wv + 4][4 * jj + 2][bb] + xg[2];
      float zo = zt[wv][4 * jj + 3][bb] + zt[wv + 4][4 * jj + 3][bb] + xg[3];
      c = sigm(zf) * c + sigm(zi) * tanhf(zg);
      float hN = sigm(zo) * tanhf(c);
      int hi_ = (int)(unsigned short)f2bf(hN);
      int lo_ = (int)(unsigned short)f2bf(hN - bf2f((short)hi_));
      int hi2 = __shfl_xor(hi_, 1), lo2 = __shfl_xor(lo_, 1);
      if ((jj & 1) == 0) {
        u64 pv = (u64)((u32)hi_ | ((u32)hi2 << 16)) | ((u64)((u32)lo_ | ((u32)lo2 << 16)) << 32);
        ic_store64(&hbuf[(size_t)(s + 1) * 4096 + ((bb * Hq + hidx) >> 1)], pv);
      }
      if (s == Tq - 1) {
        hfin[bb * Hq + hidx] = hN;
        cfin[bb * Hq + hidx] = c;
      }
    }
  }
}

// ---------------- generic cell(s): carry ready at launch; input = upstream h
// circle (hi+lo), polled (concurrent producer) or plain-loaded (materialized).
struct CellP {
  const short* ur;      // recurrent weights' (gate-interleaved, [2048][512])
  const short* wr;      // input weights'
  const float* bias;
  const float* hcar;    // carry h (f32, ready)
  const float* ccar;    // carry c
  u64*  own;            // own h circle [129][4096]
  const u64* inp;       // input h circle (consume slot s+1)
  int   inpPoll;        // 1 = sentinel-poll input (concurrent producer)
  short* seq;           // optional: hi out [T*B, H]
  short* dec;           // optional: hi out at (b*Tq+s)*(2H)
  float* hfin;          // optional finals
  float* cfin;
};
struct Params2 { CellP c[2]; };

__global__ __launch_bounds__(512, 1) void k_cells(Params2 prm) {
  __shared__ short pl[4][16][520];
  __shared__ float zt[8][16][20];
  const int grp = blockIdx.x >> 5, rank = blockIdx.x & 31;
  const CellP P = grp ? prm.c[1] : prm.c[0];
  const int tid = threadIdx.x;
  const int wv = tid >> 6, lane = tid & 63;
  const int l15 = lane & 15, l4 = lane >> 4;
  const int kh = wv >> 2;
  const int gw = rank * 4 + (wv & 3);
  const int bb = lane >> 2, jj = lane & 3;
  const int hidx = gw * 4 + jj;
  const int idx = bb * Hq + hidx;

  bfrag ur[8], wr[8];
  {
    size_t ro = (size_t)(gw * 16 + l15) * Hq + kh * 256 + l4 * 8;
    #pragma unroll
    for (int ks = 0; ks < 8; ++ks) {
      ur[ks] = *(const bfrag*)&P.ur[ro + ks * 32];
      wr[ks] = *(const bfrag*)&P.wr[ro + ks * 32];
    }
  }
  float bi = 0, bf_ = 0, bg_ = 0, bo_ = 0, c = 0.0f;
  if (wv < 4) {
    bi = P.bias[hidx]; bf_ = P.bias[Hq + hidx];
    bg_ = P.bias[2 * Hq + hidx]; bo_ = P.bias[3 * Hq + hidx];
    float hv = P.hcar[idx];
    c = P.ccar[idx];
    int hi_ = (int)(unsigned short)f2bf(hv);
    int lo_ = (int)(unsigned short)f2bf(hv - bf2f((short)hi_));
    int hi2 = __shfl_xor(hi_, 1), lo2 = __shfl_xor(lo_, 1);
    if ((jj & 1) == 0) {
      u64 v = (u64)((u32)hi_ | ((u32)hi2 << 16)) | ((u64)((u32)lo_ | ((u32)lo2 << 16)) << 32);
      ic_store64(&P.own[idx >> 1], v);
    }
  }

  for (int s = 0; s < Tq; ++s) {
    u64 v[8], vx[8];
    const u64* ph = P.own + (size_t)s * 4096 + tid;
    const u64* px = P.inp + (size_t)(s + 1) * 4096 + tid;
    if (P.inpPoll) {          // input producer concurrent: combined sentinel sweep
      for (int spin = 0;; ++spin) {
        #pragma unroll
        for (int it = 0; it < 8; ++it) v[it]  = ic_load64(&ph[it * 512]);
        #pragma unroll
        for (int it = 0; it < 8; ++it) vx[it] = ic_load64(&px[it * 512]);
        u32 bad = 0;
        #pragma unroll
        for (int it = 0; it < 8; ++it) {
          bad |= (((u32)v[it]  & 0xFFFFu) == SENTW);
          bad |= (((u32)vx[it] & 0xFFFFu) == SENTW);
        }
        if (!bad || spin >= SPINCAP) break;
        __builtin_amdgcn_s_sleep(1);
      }
    } else {                  // input fully materialized: plain cached loads
      #pragma unroll
      for (int it = 0; it < 8; ++it) vx[it] = px[it * 512];
      for (int spin = 0;; ++spin) {
        #pragma unroll
        for (int it = 0; it < 8; ++it) v[it] = ic_load64(&ph[it * 512]);
        u32 bad = 0;
        #pragma unroll
        for (int it = 0; it < 8; ++it) bad |= (((u32)v[it] & 0xFFFFu) == SENTW);
        if (!bad || spin >= SPINCAP) break;
        __builtin_amdgcn_s_sleep(1);
      }
    }
    stage_h(&pl[0][0][0], &pl[1][0][0], v);
    stage_h(&pl[2][0][0], &pl[3][0][0], vx);
    __syncthreads();

    facc a0 = {}, a1 = {}, a2 = {}, a3 = {};
    #pragma unroll
    for (int ks = 0; ks < 8; ++ks) {
      int bo = kh * 512 + ks * 64 + l4 * 16;
      bfrag hh = *(const bfrag*)swz(&pl[0][0][0], l15, bo);
      bfrag hl = *(const bfrag*)swz(&pl[1][0][0], l15, bo);
      bfrag xh = *(const bfrag*)swz(&pl[2][0][0], l15, bo);
      bfrag xl = *(const bfrag*)swz(&pl[3][0][0], l15, bo);
      a0 = __builtin_amdgcn_mfma_f32_16x16x32_bf16(hh, ur[ks], a0, 0, 0, 0);
      a1 = __builtin_amdgcn_mfma_f32_16x16x32_bf16(hl, ur[ks], a1, 0, 0, 0);
      a2 = __builtin_amdgcn_mfma_f32_16x16x32_bf16(xh, wr[ks], a2, 0, 0, 0);
      a3 = __builtin_amdgcn_mfma_f32_16x16x32_bf16(xl, wr[ks], a3, 0, 0, 0);
    }
    a0 += a1; a0 += a2; a0 += a3;
    *(f32x4*)&zt[wv][l15][l4 * 4] = a0;
    __syncthreads();

    if (wv < 4) {
      float zi = zt[wv][4 * jj + 0][bb] + zt[wv + 4][4 * jj + 0][bb] + bi;
      float zf = zt[wv][4 * jj + 1][bb] + zt[wv + 4][4 * jj + 1][bb] + bf_;
      float zg = zt[wv][4 * jj + 2][bb] + zt[wv + 4][4 * jj + 2][bb] + bg_;
      float zo = zt[wv][4 * jj + 3][bb] + zt[wv + 4][4 * jj + 3][bb] + bo_;
      c = sigm(zf) * c + sigm(zi) * tanhf(zg);
      float hN = sigm(zo) * tanhf(c);
      int hi_ = (int)(unsigned short)f2bf(hN);
      int lo_ = (int)(unsigned short)f2bf(hN - bf2f((short)hi_));
      int hi2 = __shfl_xor(hi_, 1), lo2 = __shfl_xor(lo_, 1);
      if ((jj & 1) == 0) {
        u64 pv = (u64)((u32)hi_ | ((u32)hi2 << 16)) | ((u64)((u32)lo_ | ((u32)lo2 << 16)) << 32);
        ic_store64(&P.own[(size_t)(s + 1) * 4096 + (idx >> 1)], pv);
      }
      if (P.seq) P.seq[(size_t)(s * Bq + bb) * Hq + hidx] = (short)hi_;
      if (P.dec) P.dec[((size_t)bb * Tq + s) * (2 * Hq) + hidx] = (short)hi_;
      if (s == Tq - 1 && P.hfin) {
        P.hfin[idx] = hN;
        P.cfin[idx] = c;
      }
    }
  }
}

// ---------------- batched attention over full seq2 (bf16 in/out; one block per (b,t))
__global__ __launch_bounds__(256) void k_attn(const short* __restrict__ seq2b,
                                              const short* __restrict__ hqb,
                                              short* __restrict__ decb) {
  int blk = blockIdx.x;
  int b = blk >> 7, t = blk & 127;
  __shared__ u32 q[256];
  __shared__ float part[256];
  __shared__ float p[Tq];
  int tid = threadIdx.x;
  q[tid] = *(const u32*)&hqb[(size_t)(t * Bq + b) * Hq + tid * 2];
  __syncthreads();
  {
    int s = tid >> 1, half = tid & 1;
    const u32* row = (const u32*)&seq2b[(size_t)(s * Bq + b) * Hq + half * 256];
    const u32* qh = q + half * 128;
    float a = 0.0f;
    #pragma unroll 8
    for (int k = 0; k < 128; ++k) {
      u32 r = row[k], qq = qh[k];
      a += asf(r << 16) * asf(qq << 16) + asf(r & 0xFFFF0000u) * asf(qq & 0xFFFF0000u);
    }
    part[tid] = a;
  }
  __syncthreads();
  if (tid < 64) {
    float v0 = part[2 * tid] + part[2 * tid + 1];
    float v1 = part[2 * (tid + 64)] + part[2 * (tid + 64) + 1];
    float mx = fmaxf(v0, v1);
    for (int off = 32; off; off >>= 1) mx = fmaxf(mx, __shfl_xor(mx, off));
    float e0 = __expf(v0 - mx), e1 = __expf(v1 - mx);
    float sm = e0 + e1;
    for (int off = 32; off; off >>= 1) sm += __shfl_xor(sm, off);
    float inv = 1.0f / sm;
    p[tid] = e0 * inv; p[tid + 64] = e1 * inv;
  }
  __syncthreads();
  float c0 = 0.0f, c1 = 0.0f;
  for (int s = 0; s < Tq; ++s) {
    float ps = p[s];
    u32 r = *(const u32*)&seq2b[(size_t)(s * Bq + b) * Hq + tid * 2];
    c0 += ps * asf(r << 16);
    c1 += ps * asf(r & 0xFFFF0000u);
  }
  u32 o = ((u32)(unsigned short)f2bf(c0)) | (((u32)(unsigned short)f2bf(c1)) << 16);
  *(u32*)&decb[(size_t)(b * Tq + t) * (2 * Hq) + Hq + tid * 2] = o;
}

// ---------------- row softmax over VO=32001 (in-place on d_out)
__global__ __launch_bounds__(256) void k_softmax(float* __restrict__ L) {
  int row = blockIdx.x;
  float* p = L + (size_t)row * VO;
  int tid = threadIdx.x;
  float m = -3.0e38f, s = 0.0f;
  for (int i = tid; i < VO; i += 256) {
    float v = p[i];
    float mn = fmaxf(m, v);
    s = s * __expf(m - mn) + __expf(v - mn);
    m = mn;
  }
  __shared__ float sm[256], ss[256];
  sm[tid] = m; ss[tid] = s;
  __syncthreads();
  for (int off = 128; off; off >>= 1) {
    if (tid < off) {
      float m2 = sm[tid + off], s2 = ss[tid + off];
      float mn = fmaxf(sm[tid], m2);
      ss[tid] = ss[tid] * __expf(sm[tid] - mn) + s2 * __expf(m2 - mn);
      sm[tid] = mn;
    }
    __syncthreads();
  }
  float M = sm[0], IS = 1.0f / ss[0];
  for (int i = tid; i < VO; i += 256) {
    p[i] = __expf(p[i] - M) * IS;
  }
}

// =============================================================================
extern "C" void kernel_launch(void* const* d_in, const int* in_sizes, int n_in,
                              void* d_out, int out_size, void* d_ws, size_t ws_size,
                              hipStream_t stream) {
  const int*   tokens = (const int*)d_in[0];
  const float* emb    = (const float*)d_in[1];
  const float* W1     = (const float*)d_in[2];
  const float* U1     = (const float*)d_in[3];
  const float* b1     = (const float*)d_in[4];
  const float* W2     = (const float*)d_in[5];
  const float* U2     = (const float*)d_in[6];
  const float* b2     = (const float*)d_in[7];
  const float* Wd1    = (const float*)d_in[8];
  const float* Ud1    = (const float*)d_in[9];
  const float* bd1    = (const float*)d_in[10];
  const float* Wd2    = (const float*)d_in[11];
  const float* Ud2    = (const float*)d_in[12];
  const float* bd2    = (const float*)d_in[13];
  const float* Wo     = (const float*)d_in[14];
  const float* bo     = (const float*)d_in[15];
  float* out = (float*)d_out;

  size_t off = 0;
  char* base = (char*)d_ws;
  auto alloc = [&](size_t bytes) -> void* {
    void* p = base + off;
    off += (bytes + 255) & ~(size_t)255;
    return p;
  };
  short* x_bf    = (short*)alloc((size_t)MR * Dq * 2);
  short* W1T     = (short*)alloc((size_t)G4H * Dq * 2);
  short* WoT     = (short*)alloc((size_t)NPAD * (2 * Hq) * 2);
  short* U1T     = (short*)alloc((size_t)G4H * Hq * 2);
  short* U2T     = (short*)alloc((size_t)G4H * Hq * 2);
  short* W2T     = (short*)alloc((size_t)G4H * Hq * 2);
  short* Ud1T    = (short*)alloc((size_t)G4H * Hq * 2);
  short* Wd1T    = (short*)alloc((size_t)G4H * Hq * 2);
  short* Ud2T    = (short*)alloc((size_t)G4H * Hq * 2);
  short* Wd2T    = (short*)alloc((size_t)G4H * Hq * 2);
  float* XW      = (float*)alloc((size_t)MR * G4H * 4);
  short* seq2_bf = (short*)alloc((size_t)MR * Hq * 2);
  short* hBseqbf = (short*)alloc((size_t)MR * Hq * 2);
  short* dec_bf  = (short*)alloc((size_t)MR * 2 * Hq * 2);
  u64*   hflow   = (u64*)alloc((size_t)516 * 4096 * 8);   // 4 circles x 129 slots
  float* h1f     = (float*)alloc(BH * 4);
  float* c1f     = (float*)alloc(BH * 4);
  float* h2f     = (float*)alloc(BH * 4);
  float* c2f     = (float*)alloc(BH * 4);
  u64* h1buf = hflow;
  u64* h2buf = hflow + (size_t)129 * 4096;
  u64* hAbuf = hflow + (size_t)258 * 4096;
  u64* hBbuf = hflow + (size_t)387 * 4096;
  (void)ws_size; (void)in_sizes; (void)n_in; (void)out_size;

  // per-launch sentinel reset (kernel boundary flushes before first poll)
  {
    int n64 = 516 * 4096;
    k_fill<<<(n64 + 255) / 256, 256, 0, stream>>>(hflow, n64);
  }

  // weight transposes + bf16 conversion (gate-interleave on all recurrent mats)
  k_transcvt<<<dim3(G4H / 32, Dq / 32), 256, 0, stream>>>(W1, W1T, Dq, G4H, 1);
  k_transcvt<<<dim3(G4H / 32, Hq / 32), 256, 0, stream>>>(U1, U1T, Hq, G4H, 1);
  k_transcvt<<<dim3(G4H / 32, Hq / 32), 256, 0, stream>>>(U2, U2T, Hq, G4H, 1);
  k_transcvt<<<dim3(G4H / 32, Hq / 32), 256, 0, stream>>>(W2, W2T, Hq, G4H, 1);
  k_transcvt<<<dim3(G4H / 32, Hq / 32), 256, 0, stream>>>(Ud1, Ud1T, Hq, G4H, 1);
  k_transcvt<<<dim3(G4H / 32, Hq / 32), 256, 0, stream>>>(Wd1, Wd1T, Hq, G4H, 1);
  k_transcvt<<<dim3(G4H / 32, Hq / 32), 256, 0, stream>>>(Ud2, Ud2T, Hq, G4H, 1);
  k_transcvt<<<dim3(G4H / 32, Hq / 32), 256, 0, stream>>>(Wd2, Wd2T, Hq, G4H, 1);
  k_transcvt<<<dim3(NPAD / 32, (2 * Hq) / 32), 256, 0, stream>>>(Wo, WoT, 2 * Hq, VO, 0);

  k_gather<<<MR, 256, 0, stream>>>(tokens, emb, x_bf);

  // enc1: input projection GEMM + isolated single-cell recurrence
  k_gemm<<<dim3(G4H / 128, MR / 128), 256, 0, stream>>>(x_bf, W1T, XW, b1, MR, G4H, Dq, G4H, 1);
  k_rec1<<<32, 512, 0, stream>>>(XW, U1T, h1buf, h1f, c1f);

  // enc2 (grp0) || decA (grp1): both carries = enc1 finals (ready at launch).
  // enc2 input = h1buf (materialized, plain loads); decA input = h2buf (polled).
  {
    Params2 p;
    p.c[0] = { U2T, W2T, b2,  h1f, c1f, h2buf, h1buf, 0, seq2_bf, nullptr, h2f, c2f };
    p.c[1] = { Ud1T, Wd1T, bd1, h1f, c1f, hAbuf, h2buf, 1, nullptr, nullptr, nullptr, nullptr };
    k_cells<<<64, 512, 0, stream>>>(p);
  }

  // decB: carry = enc2 finals; input = hAbuf (materialized, plain loads)
  {
    Params2 p;
    p.c[0] = { Ud2T, Wd2T, bd2, h2f, c2f, hBbuf, hAbuf, 0, hBseqbf, dec_bf, nullptr, nullptr };
    p.c[1] = p.c[0];
    k_cells<<<32, 512, 0, stream>>>(p);
  }

  // attention + logits + softmax
  k_attn<<<MR, 256, 0, stream>>>(seq2_bf, hBseqbf, dec_bf);
  k_gemm<<<dim3(NPAD / 128, MR / 128), 256, 0, stream>>>(dec_bf, WoT, out, bo, MR, VO, 2 * Hq, VO, 0);
  k_softmax<<<MR, 256, 0, stream>>>(out);
}